// Round 1
// baseline (2177.765 us; speedup 1.0000x reference)
//
#include <hip/hip_runtime.h>

#define DEVFN __device__ __forceinline__

constexpr int N    = 100000;
constexpr int F_IN = 166;
constexpr int HID  = 128;
constexpr int E    = 1600000;
constexpr int TOT  = E + N;          // edges + self-loops

// workspace layout (bytes)
constexpr size_t HW_OFF   = 0;                      // hW  [N,128] f32   51.2 MB
constexpr size_t ASRC_OFF = 51200000;               // a_src [N,4] f32    1.6 MB
constexpr size_t ADST_OFF = 52800000;               // a_dst [N,4] f32    1.6 MB
constexpr size_t OACC_OFF = 54400000;               // out_acc [N,128]   51.2 MB (zeroed)
constexpr size_t MU_OFF   = 105600000;              // m ordered-uint [N,4] (zeroed = -inf)
constexpr size_t SSUM_OFF = 107200000;              // s [N,4] f32 (zeroed)
constexpr size_t ZERO_BYTES = 54400000;             // OACC..end contiguous zero region

DEVFN unsigned f2ord(float f) {
    unsigned u = __float_as_uint(f);
    return (u & 0x80000000u) ? ~u : (u | 0x80000000u);
}
DEVFN float ord2f(unsigned u) {
    return (u & 0x80000000u) ? __uint_as_float(u & 0x7FFFFFFFu) : __uint_as_float(~u);
}
DEVFN float lrelu(float e) { return e > 0.0f ? e : 0.2f * e; }

// ---------------------------------------------------------------------------
// K12: h = relu(x@W_in+b_in) (kept in LDS), hW = h@W_gat, a_src/a_dst = hW·att
// tile: 16 rows x 128 cols, 256 threads, 8 rows/thread register blocking
// ---------------------------------------------------------------------------
__global__ __launch_bounds__(256) void k_proj(
    const float* __restrict__ x, const float* __restrict__ Win,
    const float* __restrict__ bin, const float* __restrict__ Wgat,
    const float* __restrict__ attS, const float* __restrict__ attD,
    float* __restrict__ hW, float* __restrict__ aS, float* __restrict__ aD)
{
    __shared__ __align__(16) float xs[16 * 168];   // x tile, padded
    __shared__ __align__(16) float hs[16 * 136];   // h tile, padded (16B-aligned rows)
    const int t = threadIdx.x;
    const int row0 = blockIdx.x * 16;

    for (int idx = t; idx < 16 * F_IN; idx += 256) {
        int r = idx / F_IN, k = idx - r * F_IN;
        xs[r * 168 + k] = x[(size_t)(row0 + r) * F_IN + k];
    }
    __syncthreads();

    const int col = t & 127, half = t >> 7, rbase = half * 8;

    float acc[8];
#pragma unroll
    for (int r = 0; r < 8; ++r) acc[r] = 0.0f;

    for (int k = 0; k < F_IN; k += 2) {
        float w0 = Win[k * HID + col];
        float w1 = Win[(k + 1) * HID + col];
#pragma unroll
        for (int r = 0; r < 8; ++r) {
            const float2 xv = *(const float2*)&xs[(rbase + r) * 168 + k];
            acc[r] = fmaf(xv.x, w0, fmaf(xv.y, w1, acc[r]));
        }
    }
    const float bb = bin[col];
#pragma unroll
    for (int r = 0; r < 8; ++r) {
        float h = acc[r] + bb;
        hs[(rbase + r) * 136 + col] = h > 0.0f ? h : 0.0f;
    }
    __syncthreads();

    float acc2[8];
#pragma unroll
    for (int r = 0; r < 8; ++r) acc2[r] = 0.0f;

    for (int k = 0; k < HID; k += 4) {
        float w0 = Wgat[(k + 0) * HID + col];
        float w1 = Wgat[(k + 1) * HID + col];
        float w2 = Wgat[(k + 2) * HID + col];
        float w3 = Wgat[(k + 3) * HID + col];
#pragma unroll
        for (int r = 0; r < 8; ++r) {
            const float4 hv = *(const float4*)&hs[(rbase + r) * 136 + k];
            acc2[r] = fmaf(hv.x, w0, fmaf(hv.y, w1, fmaf(hv.z, w2, fmaf(hv.w, w3, acc2[r]))));
        }
    }

    const float as = attS[col], ad = attD[col];
    const int lane = t & 63, head = col >> 5;
#pragma unroll
    for (int r = 0; r < 8; ++r) {
        const int row = row0 + rbase + r;
        const float v = acc2[r];
        hW[(size_t)row * HID + col] = v;
        float cs = v * as, cd = v * ad;
#pragma unroll
        for (int off = 16; off >= 1; off >>= 1) {
            cs += __shfl_xor(cs, off);
            cd += __shfl_xor(cd, off);
        }
        if ((lane & 31) == 0) {
            aS[row * 4 + head] = cs;
            aD[row * 4 + head] = cd;
        }
    }
}

// ---------------------------------------------------------------------------
// K4: segment-max of leaky_relu(a_src[s]+a_dst[d]) into ordered-uint m[d]
// ---------------------------------------------------------------------------
__global__ __launch_bounds__(256) void k_max(
    const int* __restrict__ ei, const float4* __restrict__ aS,
    const float4* __restrict__ aD, unsigned* __restrict__ mu)
{
    int i = blockIdx.x * 256 + threadIdx.x;
    if (i >= TOT) return;
    int s, d;
    if (i < E) { s = ei[i]; d = ei[E + i]; } else { s = i - E; d = s; }
    const float4 a = aS[s], b = aD[d];
    atomicMax(&mu[d * 4 + 0], f2ord(lrelu(a.x + b.x)));
    atomicMax(&mu[d * 4 + 1], f2ord(lrelu(a.y + b.y)));
    atomicMax(&mu[d * 4 + 2], f2ord(lrelu(a.z + b.z)));
    atomicMax(&mu[d * 4 + 3], f2ord(lrelu(a.w + b.w)));
}

// ---------------------------------------------------------------------------
// K5: one wave per edge: ex = exp(e - m[d]); s[d]+=ex; out_acc[d] += ex*hW[s]
// ---------------------------------------------------------------------------
__global__ __launch_bounds__(256) void k_agg(
    const int* __restrict__ ei, const float4* __restrict__ aS,
    const float4* __restrict__ aD, const uint4* __restrict__ mu,
    const float2* __restrict__ hW2, float* __restrict__ ssum,
    float* __restrict__ oacc)
{
    const int i = blockIdx.x * 4 + (threadIdx.x >> 6);
    if (i >= TOT) return;
    const int lane = threadIdx.x & 63;
    int s, d;
    if (i < E) { s = ei[i]; d = ei[E + i]; } else { s = i - E; d = s; }

    const float4 a = aS[s], b = aD[d];
    const uint4 m = mu[d];
    const float x0 = __expf(lrelu(a.x + b.x) - ord2f(m.x));
    const float x1 = __expf(lrelu(a.y + b.y) - ord2f(m.y));
    const float x2 = __expf(lrelu(a.z + b.z) - ord2f(m.z));
    const float x3 = __expf(lrelu(a.w + b.w) - ord2f(m.w));

    if (lane < 4) {
        float v = (lane == 0) ? x0 : (lane == 1) ? x1 : (lane == 2) ? x2 : x3;
        unsafeAtomicAdd(&ssum[d * 4 + lane], v);
    }
    const float2 hv = hW2[(size_t)s * 64 + lane];
    const int hd = lane >> 4;
    const float f = (hd == 0) ? x0 : (hd == 1) ? x1 : (hd == 2) ? x2 : x3;
    float* po = oacc + (size_t)d * HID + lane * 2;
    unsafeAtomicAdd(po, hv.x * f);
    unsafeAtomicAdd(po + 1, hv.y * f);
}

// ---------------------------------------------------------------------------
// K6: out = oacc/(s+1e-16)+b_gat; h2 = relu(out@W1+b1); logits = h2@W2+b2
// one wave per node, W1 staged in LDS
// ---------------------------------------------------------------------------
__global__ __launch_bounds__(256) void k_mlp(
    const float* __restrict__ oacc, const float4* __restrict__ ssum,
    const float* __restrict__ bgat, const float* __restrict__ W1,
    const float* __restrict__ b1, const float* __restrict__ W2,
    const float* __restrict__ b2, float2* __restrict__ out)
{
    __shared__ __align__(16) float W1l[HID * 64];
    __shared__ __align__(16) float bufs[4][HID];
    __shared__ float b1l[64];
    __shared__ float W2l[128];
    __shared__ float b2l[2];

    const int t = threadIdx.x;
    for (int idx = t; idx < HID * 64; idx += 256) W1l[idx] = W1[idx];
    if (t < 64) b1l[t] = b1[t];
    if (t < 128) W2l[t] = W2[t];
    if (t < 2) b2l[t] = b2[t];

    const int w = t >> 6, lane = t & 63;
    const int n = blockIdx.x * 4 + w;

    const float4 s4 = ssum[n];
    const int hd = lane >> 4;
    const float denom = ((hd == 0) ? s4.x : (hd == 1) ? s4.y : (hd == 2) ? s4.z : s4.w) + 1e-16f;
    const float2 oa = *(const float2*)&oacc[(size_t)n * HID + lane * 2];
    const float2 bg = *(const float2*)&bgat[lane * 2];
    bufs[w][lane * 2 + 0] = oa.x / denom + bg.x;
    bufs[w][lane * 2 + 1] = oa.y / denom + bg.y;
    __syncthreads();

    float acc = b1l[lane];
#pragma unroll 4
    for (int j = 0; j < HID; j += 4) {
        const float4 bv = *(const float4*)&bufs[w][j];
        acc = fmaf(bv.x, W1l[(j + 0) * 64 + lane], acc);
        acc = fmaf(bv.y, W1l[(j + 1) * 64 + lane], acc);
        acc = fmaf(bv.z, W1l[(j + 2) * 64 + lane], acc);
        acc = fmaf(bv.w, W1l[(j + 3) * 64 + lane], acc);
    }
    acc = acc > 0.0f ? acc : 0.0f;

    float l0 = acc * W2l[lane * 2 + 0];
    float l1 = acc * W2l[lane * 2 + 1];
#pragma unroll
    for (int off = 32; off >= 1; off >>= 1) {
        l0 += __shfl_xor(l0, off);
        l1 += __shfl_xor(l1, off);
    }
    if (lane == 0) out[n] = make_float2(l0 + b2l[0], l1 + b2l[1]);
}

extern "C" void kernel_launch(void* const* d_in, const int* in_sizes, int n_in,
                              void* d_out, int out_size, void* d_ws, size_t ws_size,
                              hipStream_t stream) {
    const float* x     = (const float*)d_in[0];
    const int*   ei    = (const int*)d_in[1];
    const float* Win   = (const float*)d_in[2];
    const float* bin   = (const float*)d_in[3];
    const float* Wgat  = (const float*)d_in[4];
    const float* attS  = (const float*)d_in[5];
    const float* attD  = (const float*)d_in[6];
    const float* bgat  = (const float*)d_in[7];
    const float* W1    = (const float*)d_in[8];
    const float* b1    = (const float*)d_in[9];
    const float* W2    = (const float*)d_in[10];
    const float* b2    = (const float*)d_in[11];

    char* ws = (char*)d_ws;
    float*    hW   = (float*)(ws + HW_OFF);
    float*    aS   = (float*)(ws + ASRC_OFF);
    float*    aD   = (float*)(ws + ADST_OFF);
    float*    oacc = (float*)(ws + OACC_OFF);
    unsigned* mu   = (unsigned*)(ws + MU_OFF);
    float*    ssum = (float*)(ws + SSUM_OFF);

    // zero out_acc + m (ordered-uint 0 == -inf) + s in one contiguous memset
    hipMemsetAsync(ws + OACC_OFF, 0, ZERO_BYTES, stream);

    k_proj<<<N / 16, 256, 0, stream>>>(x, Win, bin, Wgat, attS, attD, hW, aS, aD);
    k_max<<<(TOT + 255) / 256, 256, 0, stream>>>(ei, (const float4*)aS, (const float4*)aD, mu);
    k_agg<<<TOT / 4, 256, 0, stream>>>(ei, (const float4*)aS, (const float4*)aD,
                                       (const uint4*)mu, (const float2*)hW, ssum, oacc);
    k_mlp<<<N / 4, 256, 0, stream>>>(oacc, (const float4*)ssum, bgat, W1, b1, W2, b2,
                                     (float2*)d_out);
}

// Round 2
// 895.882 us; speedup vs baseline: 2.4309x; 2.4309x over previous
//
#include <hip/hip_runtime.h>

#define DEVFN __device__ __forceinline__

constexpr int N    = 100000;
constexpr int F_IN = 166;
constexpr int HID  = 128;
constexpr int E    = 1600000;
constexpr int TOT  = E + N;          // edges + self-loops

// ---- workspace layout (bytes, all 16B-aligned) ----
constexpr size_t HW_OFF   = 0;            // hW [N,128] f32      51.2 MB
constexpr size_t ASRC_OFF = 51200000;     // a_src [N,4] f32      1.6 MB
constexpr size_t ADST_OFF = 52800000;     // a_dst [N,4] f32      1.6 MB
constexpr size_t DEG_OFF  = 54400000;     // deg [N] i32        400 KB (zeroed)
constexpr size_t ROW_OFF  = 54800000;     // rowstart [N+1] i32
constexpr size_t CUR_OFF  = 55300000;     // cursor [N] i32
constexpr size_t BSUM_OFF = 55700000;     // block sums [128] i32
constexpr size_t CSR_OFF  = 55710000;     // csr_src [TOT] i32   27.2 MB

constexpr int SCAN_ELEMS = 1024;                       // per scan block
constexpr int SCAN_NB    = (N + SCAN_ELEMS - 1) / SCAN_ELEMS;  // 98

DEVFN float lrelu(float e) { return e > 0.0f ? e : 0.2f * e; }

// ---------------------------------------------------------------------------
// K1: h = relu(x@W_in+b_in) (in LDS), hW = h@W_gat, a_src/a_dst = hW·att
// ---------------------------------------------------------------------------
__global__ __launch_bounds__(256) void k_proj(
    const float* __restrict__ x, const float* __restrict__ Win,
    const float* __restrict__ bin, const float* __restrict__ Wgat,
    const float* __restrict__ attS, const float* __restrict__ attD,
    float* __restrict__ hW, float* __restrict__ aS, float* __restrict__ aD)
{
    __shared__ __align__(16) float xs[16 * 168];
    __shared__ __align__(16) float hs[16 * 136];
    const int t = threadIdx.x;
    const int row0 = blockIdx.x * 16;

    for (int idx = t; idx < 16 * F_IN; idx += 256) {
        int r = idx / F_IN, k = idx - r * F_IN;
        xs[r * 168 + k] = x[(size_t)(row0 + r) * F_IN + k];
    }
    __syncthreads();

    const int col = t & 127, half = t >> 7, rbase = half * 8;

    float acc[8];
#pragma unroll
    for (int r = 0; r < 8; ++r) acc[r] = 0.0f;

    for (int k = 0; k < F_IN; k += 2) {
        float w0 = Win[k * HID + col];
        float w1 = Win[(k + 1) * HID + col];
#pragma unroll
        for (int r = 0; r < 8; ++r) {
            const float2 xv = *(const float2*)&xs[(rbase + r) * 168 + k];
            acc[r] = fmaf(xv.x, w0, fmaf(xv.y, w1, acc[r]));
        }
    }
    const float bb = bin[col];
#pragma unroll
    for (int r = 0; r < 8; ++r) {
        float h = acc[r] + bb;
        hs[(rbase + r) * 136 + col] = h > 0.0f ? h : 0.0f;
    }
    __syncthreads();

    float acc2[8];
#pragma unroll
    for (int r = 0; r < 8; ++r) acc2[r] = 0.0f;

    for (int k = 0; k < HID; k += 4) {
        float w0 = Wgat[(k + 0) * HID + col];
        float w1 = Wgat[(k + 1) * HID + col];
        float w2 = Wgat[(k + 2) * HID + col];
        float w3 = Wgat[(k + 3) * HID + col];
#pragma unroll
        for (int r = 0; r < 8; ++r) {
            const float4 hv = *(const float4*)&hs[(rbase + r) * 136 + k];
            acc2[r] = fmaf(hv.x, w0, fmaf(hv.y, w1, fmaf(hv.z, w2, fmaf(hv.w, w3, acc2[r]))));
        }
    }

    const float as = attS[col], ad = attD[col];
    const int lane = t & 63, head = col >> 5;
#pragma unroll
    for (int r = 0; r < 8; ++r) {
        const int row = row0 + rbase + r;
        const float v = acc2[r];
        hW[(size_t)row * HID + col] = v;
        float cs = v * as, cd = v * ad;
#pragma unroll
        for (int off = 16; off >= 1; off >>= 1) {
            cs += __shfl_xor(cs, off);
            cd += __shfl_xor(cd, off);
        }
        if ((lane & 31) == 0) {
            aS[row * 4 + head] = cs;
            aD[row * 4 + head] = cd;
        }
    }
}

// ---------------------------------------------------------------------------
// CSR build
// ---------------------------------------------------------------------------
__global__ __launch_bounds__(256) void k_hist(const int* __restrict__ ei,
                                              int* __restrict__ deg)
{
    int i = blockIdx.x * 256 + threadIdx.x;
    if (i >= TOT) return;
    int d = (i < E) ? ei[E + i] : (i - E);
    atomicAdd(&deg[d], 1);
}

__global__ __launch_bounds__(256) void k_scan1(const int* __restrict__ deg,
                                               int* __restrict__ bsum)
{
    __shared__ int sd[256];
    const int t = threadIdx.x, b = blockIdx.x;
    int s = 0;
    int i0 = b * SCAN_ELEMS + t * 4;
#pragma unroll
    for (int k = 0; k < 4; ++k) {
        int i = i0 + k;
        s += (i < N) ? deg[i] : 0;
    }
    sd[t] = s;
    __syncthreads();
    for (int off = 128; off >= 1; off >>= 1) {
        if (t < off) sd[t] += sd[t + off];
        __syncthreads();
    }
    if (t == 0) bsum[b] = sd[0];
}

__global__ void k_scan2(int* __restrict__ bsum, int* __restrict__ rowstart)
{
    if (threadIdx.x == 0) {
        int run = 0;
        for (int b = 0; b < SCAN_NB; ++b) {
            int v = bsum[b];
            bsum[b] = run;
            run += v;
        }
        rowstart[N] = run;  // == TOT
    }
}

__global__ __launch_bounds__(256) void k_scan3(const int* __restrict__ deg,
                                               const int* __restrict__ boff,
                                               int* __restrict__ rowstart,
                                               int* __restrict__ cursor)
{
    __shared__ int sd[256];
    const int t = threadIdx.x, b = blockIdx.x;
    const int i0 = b * SCAN_ELEMS + t * 4;
    int d0 = (i0 + 0 < N) ? deg[i0 + 0] : 0;
    int d1 = (i0 + 1 < N) ? deg[i0 + 1] : 0;
    int d2 = (i0 + 2 < N) ? deg[i0 + 2] : 0;
    int d3 = (i0 + 3 < N) ? deg[i0 + 3] : 0;
    int tsum = d0 + d1 + d2 + d3;
    sd[t] = tsum;
    __syncthreads();
    // Hillis-Steele inclusive scan over 256 thread sums
    for (int off = 1; off < 256; off <<= 1) {
        int v = (t >= off) ? sd[t - off] : 0;
        __syncthreads();
        sd[t] += v;
        __syncthreads();
    }
    int base = boff[b] + sd[t] - tsum;   // exclusive prefix for this thread
    int e0 = base, e1 = base + d0, e2 = e1 + d1, e3 = e2 + d2;
    if (i0 + 0 < N) { rowstart[i0 + 0] = e0; cursor[i0 + 0] = e0; }
    if (i0 + 1 < N) { rowstart[i0 + 1] = e1; cursor[i0 + 1] = e1; }
    if (i0 + 2 < N) { rowstart[i0 + 2] = e2; cursor[i0 + 2] = e2; }
    if (i0 + 3 < N) { rowstart[i0 + 3] = e3; cursor[i0 + 3] = e3; }
}

__global__ __launch_bounds__(256) void k_scatter(const int* __restrict__ ei,
                                                 int* __restrict__ cursor,
                                                 int* __restrict__ csr)
{
    int i = blockIdx.x * 256 + threadIdx.x;
    if (i >= TOT) return;
    int s, d;
    if (i < E) { s = ei[i]; d = ei[E + i]; } else { s = i - E; d = s; }
    int pos = atomicAdd(&cursor[d], 1);
    csr[pos] = s;
}

// ---------------------------------------------------------------------------
// K_gat: one wave per dst node; two-pass softmax + aggregate in registers;
// fused MLP head (W1 in LDS). 16 nodes/block (4 waves x 4 iters).
// ---------------------------------------------------------------------------
__global__ __launch_bounds__(256) void k_gat(
    const int* __restrict__ rowstart, const int* __restrict__ csr,
    const float4* __restrict__ aS, const float4* __restrict__ aD,
    const float2* __restrict__ hW2, const float* __restrict__ bgat,
    const float* __restrict__ W1, const float* __restrict__ b1,
    const float* __restrict__ W2, const float* __restrict__ b2,
    float2* __restrict__ out)
{
    __shared__ __align__(16) float W1l[HID * 64];
    __shared__ __align__(16) float rowbuf[4][HID];
    __shared__ float b1l[64];
    __shared__ float W2l[128];
    __shared__ float b2l[2];

    const int t = threadIdx.x;
    for (int idx = t; idx < HID * 64; idx += 256) W1l[idx] = W1[idx];
    if (t < 64) b1l[t] = b1[t];
    if (t < 128) W2l[t] = W2[t];
    if (t < 2) b2l[t] = b2[t];
    __syncthreads();

    const int w = t >> 6, lane = t & 63;
    const int hd = lane >> 4;                 // head for cols 2*lane, 2*lane+1
    const float2 bg = *(const float2*)&bgat[lane * 2];

    for (int it = 0; it < 4; ++it) {
        const int n = blockIdx.x * 16 + w * 4 + it;
        const int r0 = rowstart[n], r1 = rowstart[n + 1];
        const float4 ad = aD[n];

        // ---- pass 1: per-head max over edges (lane-strided) ----
        float m0 = -INFINITY, m1 = -INFINITY, m2 = -INFINITY, m3 = -INFINITY;
        for (int j = r0 + lane; j < r1; j += 64) {
            const int s = csr[j];
            const float4 a = aS[s];
            m0 = fmaxf(m0, lrelu(a.x + ad.x));
            m1 = fmaxf(m1, lrelu(a.y + ad.y));
            m2 = fmaxf(m2, lrelu(a.z + ad.z));
            m3 = fmaxf(m3, lrelu(a.w + ad.w));
        }
#pragma unroll
        for (int off = 32; off >= 1; off >>= 1) {
            m0 = fmaxf(m0, __shfl_xor(m0, off));
            m1 = fmaxf(m1, __shfl_xor(m1, off));
            m2 = fmaxf(m2, __shfl_xor(m2, off));
            m3 = fmaxf(m3, __shfl_xor(m3, off));
        }

        // ---- pass 2: exp + weighted accumulate (whole wave per edge) ----
        float acc0 = 0.0f, acc1 = 0.0f, ss = 0.0f;
        for (int j = r0; j < r1; ++j) {
            const int s = csr[j];
            const float4 a = aS[s];
            const float x0 = __expf(lrelu(a.x + ad.x) - m0);
            const float x1 = __expf(lrelu(a.y + ad.y) - m1);
            const float x2 = __expf(lrelu(a.z + ad.z) - m2);
            const float x3 = __expf(lrelu(a.w + ad.w) - m3);
            const float f = (hd == 0) ? x0 : (hd == 1) ? x1 : (hd == 2) ? x2 : x3;
            const float2 hv = hW2[(size_t)s * 64 + lane];
            acc0 = fmaf(hv.x, f, acc0);
            acc1 = fmaf(hv.y, f, acc1);
            ss += f;
        }
        const float inv = 1.0f / (ss + 1e-16f);
        rowbuf[w][lane * 2 + 0] = acc0 * inv + bg.x;
        rowbuf[w][lane * 2 + 1] = acc1 * inv + bg.y;

        // ---- fused MLP head: h2 = relu(row@W1+b1); logits = h2@W2+b2 ----
        float acc = b1l[lane];
#pragma unroll 4
        for (int k = 0; k < HID; k += 4) {
            const float4 bv = *(const float4*)&rowbuf[w][k];
            acc = fmaf(bv.x, W1l[(k + 0) * 64 + lane], acc);
            acc = fmaf(bv.y, W1l[(k + 1) * 64 + lane], acc);
            acc = fmaf(bv.z, W1l[(k + 2) * 64 + lane], acc);
            acc = fmaf(bv.w, W1l[(k + 3) * 64 + lane], acc);
        }
        acc = acc > 0.0f ? acc : 0.0f;

        float l0 = acc * W2l[lane * 2 + 0];
        float l1 = acc * W2l[lane * 2 + 1];
#pragma unroll
        for (int off = 32; off >= 1; off >>= 1) {
            l0 += __shfl_xor(l0, off);
            l1 += __shfl_xor(l1, off);
        }
        if (lane == 0) out[n] = make_float2(l0 + b2l[0], l1 + b2l[1]);
    }
}

extern "C" void kernel_launch(void* const* d_in, const int* in_sizes, int n_in,
                              void* d_out, int out_size, void* d_ws, size_t ws_size,
                              hipStream_t stream) {
    const float* x     = (const float*)d_in[0];
    const int*   ei    = (const int*)d_in[1];
    const float* Win   = (const float*)d_in[2];
    const float* bin   = (const float*)d_in[3];
    const float* Wgat  = (const float*)d_in[4];
    const float* attS  = (const float*)d_in[5];
    const float* attD  = (const float*)d_in[6];
    const float* bgat  = (const float*)d_in[7];
    const float* W1    = (const float*)d_in[8];
    const float* b1    = (const float*)d_in[9];
    const float* W2    = (const float*)d_in[10];
    const float* b2    = (const float*)d_in[11];

    char* ws = (char*)d_ws;
    float* hW    = (float*)(ws + HW_OFF);
    float* aS    = (float*)(ws + ASRC_OFF);
    float* aD    = (float*)(ws + ADST_OFF);
    int*   deg   = (int*)(ws + DEG_OFF);
    int*   row   = (int*)(ws + ROW_OFF);
    int*   cur   = (int*)(ws + CUR_OFF);
    int*   bsum  = (int*)(ws + BSUM_OFF);
    int*   csr   = (int*)(ws + CSR_OFF);

    hipMemsetAsync(ws + DEG_OFF, 0, N * sizeof(int), stream);

    k_proj<<<N / 16, 256, 0, stream>>>(x, Win, bin, Wgat, attS, attD, hW, aS, aD);
    k_hist<<<(TOT + 255) / 256, 256, 0, stream>>>(ei, deg);
    k_scan1<<<SCAN_NB, 256, 0, stream>>>(deg, bsum);
    k_scan2<<<1, 64, 0, stream>>>(bsum, row);
    k_scan3<<<SCAN_NB, 256, 0, stream>>>(deg, bsum, row, cur);
    k_scatter<<<(TOT + 255) / 256, 256, 0, stream>>>(ei, cur, csr);
    k_gat<<<N / 16, 256, 0, stream>>>(row, csr, (const float4*)aS, (const float4*)aD,
                                      (const float2*)hW, bgat, W1, b1, W2, b2,
                                      (float2*)d_out);
}

// Round 3
// 738.202 us; speedup vs baseline: 2.9501x; 1.2136x over previous
//
#include <hip/hip_runtime.h>

#define DEVFN __device__ __forceinline__

constexpr int N    = 100000;
constexpr int F_IN = 166;
constexpr int HID  = 128;
constexpr int E    = 1600000;
constexpr int TOT  = E + N;          // edges + self-loops

// ---- workspace layout (bytes, all 16B-aligned) ----
constexpr size_t HW_OFF   = 0;            // hW [N,128] f32      51.2 MB
constexpr size_t ASRC_OFF = 51200000;     // a_src [N,4] f32      1.6 MB
constexpr size_t ADST_OFF = 52800000;     // a_dst [N,4] f32      1.6 MB
constexpr size_t DEG_OFF  = 54400000;     // deg [N] i32        400 KB (zeroed)
constexpr size_t ROW_OFF  = 54800000;     // rowstart [N+1] i32
constexpr size_t CUR_OFF  = 55300000;     // cursor [N] i32
constexpr size_t BSUM_OFF = 55700000;     // block sums [128] i32
constexpr size_t CSR_OFF  = 55710000;     // csr_src [TOT] i32   27.2 MB
constexpr size_t GOUT_OFF = 82910016;     // gat out [N,128] f32 51.2 MB

constexpr int SCAN_ELEMS = 1024;
constexpr int SCAN_NB    = (N + SCAN_ELEMS - 1) / SCAN_ELEMS;  // 98

DEVFN float lrelu(float e) { return e > 0.0f ? e : 0.2f * e; }

// ---------------------------------------------------------------------------
// K1: h = relu(x@W_in+b_in) (in LDS), hW = h@W_gat, a_src/a_dst = hW·att
// ---------------------------------------------------------------------------
__global__ __launch_bounds__(256) void k_proj(
    const float* __restrict__ x, const float* __restrict__ Win,
    const float* __restrict__ bin, const float* __restrict__ Wgat,
    const float* __restrict__ attS, const float* __restrict__ attD,
    float* __restrict__ hW, float* __restrict__ aS, float* __restrict__ aD)
{
    __shared__ __align__(16) float xs[16 * 168];
    __shared__ __align__(16) float hs[16 * 136];
    const int t = threadIdx.x;
    const int row0 = blockIdx.x * 16;

    for (int idx = t; idx < 16 * F_IN; idx += 256) {
        int r = idx / F_IN, k = idx - r * F_IN;
        xs[r * 168 + k] = x[(size_t)(row0 + r) * F_IN + k];
    }
    __syncthreads();

    const int col = t & 127, half = t >> 7, rbase = half * 8;

    float acc[8];
#pragma unroll
    for (int r = 0; r < 8; ++r) acc[r] = 0.0f;

    for (int k = 0; k < F_IN; k += 2) {
        float w0 = Win[k * HID + col];
        float w1 = Win[(k + 1) * HID + col];
#pragma unroll
        for (int r = 0; r < 8; ++r) {
            const float2 xv = *(const float2*)&xs[(rbase + r) * 168 + k];
            acc[r] = fmaf(xv.x, w0, fmaf(xv.y, w1, acc[r]));
        }
    }
    const float bb = bin[col];
#pragma unroll
    for (int r = 0; r < 8; ++r) {
        float h = acc[r] + bb;
        hs[(rbase + r) * 136 + col] = h > 0.0f ? h : 0.0f;
    }
    __syncthreads();

    float acc2[8];
#pragma unroll
    for (int r = 0; r < 8; ++r) acc2[r] = 0.0f;

    for (int k = 0; k < HID; k += 4) {
        float w0 = Wgat[(k + 0) * HID + col];
        float w1 = Wgat[(k + 1) * HID + col];
        float w2 = Wgat[(k + 2) * HID + col];
        float w3 = Wgat[(k + 3) * HID + col];
#pragma unroll
        for (int r = 0; r < 8; ++r) {
            const float4 hv = *(const float4*)&hs[(rbase + r) * 136 + k];
            acc2[r] = fmaf(hv.x, w0, fmaf(hv.y, w1, fmaf(hv.z, w2, fmaf(hv.w, w3, acc2[r]))));
        }
    }

    const float as = attS[col], ad = attD[col];
    const int lane = t & 63, head = col >> 5;
#pragma unroll
    for (int r = 0; r < 8; ++r) {
        const int row = row0 + rbase + r;
        const float v = acc2[r];
        hW[(size_t)row * HID + col] = v;
        float cs = v * as, cd = v * ad;
#pragma unroll
        for (int off = 16; off >= 1; off >>= 1) {
            cs += __shfl_xor(cs, off);
            cd += __shfl_xor(cd, off);
        }
        if ((lane & 31) == 0) {
            aS[row * 4 + head] = cs;
            aD[row * 4 + head] = cd;
        }
    }
}

// ---------------------------------------------------------------------------
// CSR build
// ---------------------------------------------------------------------------
__global__ __launch_bounds__(256) void k_hist(const int* __restrict__ ei,
                                              int* __restrict__ deg)
{
    int i = blockIdx.x * 256 + threadIdx.x;
    if (i >= TOT) return;
    int d = (i < E) ? ei[E + i] : (i - E);
    atomicAdd(&deg[d], 1);
}

__global__ __launch_bounds__(256) void k_scan1(const int* __restrict__ deg,
                                               int* __restrict__ bsum)
{
    __shared__ int sd[256];
    const int t = threadIdx.x, b = blockIdx.x;
    int s = 0;
    int i0 = b * SCAN_ELEMS + t * 4;
#pragma unroll
    for (int k = 0; k < 4; ++k) {
        int i = i0 + k;
        s += (i < N) ? deg[i] : 0;
    }
    sd[t] = s;
    __syncthreads();
    for (int off = 128; off >= 1; off >>= 1) {
        if (t < off) sd[t] += sd[t + off];
        __syncthreads();
    }
    if (t == 0) bsum[b] = sd[0];
}

__global__ void k_scan2(int* __restrict__ bsum, int* __restrict__ rowstart)
{
    if (threadIdx.x == 0) {
        int run = 0;
        for (int b = 0; b < SCAN_NB; ++b) {
            int v = bsum[b];
            bsum[b] = run;
            run += v;
        }
        rowstart[N] = run;  // == TOT
    }
}

__global__ __launch_bounds__(256) void k_scan3(const int* __restrict__ deg,
                                               const int* __restrict__ boff,
                                               int* __restrict__ rowstart,
                                               int* __restrict__ cursor)
{
    __shared__ int sd[256];
    const int t = threadIdx.x, b = blockIdx.x;
    const int i0 = b * SCAN_ELEMS + t * 4;
    int d0 = (i0 + 0 < N) ? deg[i0 + 0] : 0;
    int d1 = (i0 + 1 < N) ? deg[i0 + 1] : 0;
    int d2 = (i0 + 2 < N) ? deg[i0 + 2] : 0;
    int d3 = (i0 + 3 < N) ? deg[i0 + 3] : 0;
    int tsum = d0 + d1 + d2 + d3;
    sd[t] = tsum;
    __syncthreads();
    for (int off = 1; off < 256; off <<= 1) {
        int v = (t >= off) ? sd[t - off] : 0;
        __syncthreads();
        sd[t] += v;
        __syncthreads();
    }
    int base = boff[b] + sd[t] - tsum;
    int e0 = base, e1 = base + d0, e2 = e1 + d1, e3 = e2 + d2;
    if (i0 + 0 < N) { rowstart[i0 + 0] = e0; cursor[i0 + 0] = e0; }
    if (i0 + 1 < N) { rowstart[i0 + 1] = e1; cursor[i0 + 1] = e1; }
    if (i0 + 2 < N) { rowstart[i0 + 2] = e2; cursor[i0 + 2] = e2; }
    if (i0 + 3 < N) { rowstart[i0 + 3] = e3; cursor[i0 + 3] = e3; }
}

__global__ __launch_bounds__(256) void k_scatter(const int* __restrict__ ei,
                                                 int* __restrict__ cursor,
                                                 int* __restrict__ csr)
{
    int i = blockIdx.x * 256 + threadIdx.x;
    if (i >= TOT) return;
    int s, d;
    if (i < E) { s = ei[i]; d = ei[E + i]; } else { s = i - E; d = s; }
    int pos = atomicAdd(&cursor[d], 1);
    csr[pos] = s;
}

// ---------------------------------------------------------------------------
// K_agg: one wave per dst node; lane = slot(4) x colgroup(16); 4 edges in
// flight x unroll 2 = 8 outstanding hW-row gathers. No max pass (|e| < 1,
// exp cannot overflow; softmax is shift-invariant). No LDS -> full occupancy.
// Writes normalized GAT output (+ b_gat) row [128] to gout.
// ---------------------------------------------------------------------------
__global__ __launch_bounds__(256) void k_agg(
    const int* __restrict__ rowstart, const int* __restrict__ csr,
    const float* __restrict__ aS, const float* __restrict__ aD,
    const float4* __restrict__ hW4, const float4* __restrict__ bgat4,
    float4* __restrict__ gout4)
{
    const int t = threadIdx.x;
    const int n = blockIdx.x * 4 + (t >> 6);
    const int lane = t & 63;
    const int slot = lane >> 4;      // which of 4 parallel edges
    const int cg   = lane & 15;      // colgroup: cols [cg*8, cg*8+8)
    const int head = cg >> 2;

    const int r0 = rowstart[n], r1 = rowstart[n + 1];
    const float adh = aD[n * 4 + head];

    float4 acc0 = {0.f, 0.f, 0.f, 0.f};
    float4 acc1 = {0.f, 0.f, 0.f, 0.f};
    float ss = 0.0f;

    int j = r0 + slot;
    for (; j + 4 < r1; j += 8) {
        const int s0 = csr[j], s1 = csr[j + 4];
        const float x0 = __expf(lrelu(aS[s0 * 4 + head] + adh));
        const float x1 = __expf(lrelu(aS[s1 * 4 + head] + adh));
        const float4 ha0 = hW4[(size_t)s0 * 32 + cg * 2 + 0];
        const float4 hb0 = hW4[(size_t)s0 * 32 + cg * 2 + 1];
        const float4 ha1 = hW4[(size_t)s1 * 32 + cg * 2 + 0];
        const float4 hb1 = hW4[(size_t)s1 * 32 + cg * 2 + 1];
        acc0.x = fmaf(ha0.x, x0, acc0.x); acc0.y = fmaf(ha0.y, x0, acc0.y);
        acc0.z = fmaf(ha0.z, x0, acc0.z); acc0.w = fmaf(ha0.w, x0, acc0.w);
        acc1.x = fmaf(hb0.x, x0, acc1.x); acc1.y = fmaf(hb0.y, x0, acc1.y);
        acc1.z = fmaf(hb0.z, x0, acc1.z); acc1.w = fmaf(hb0.w, x0, acc1.w);
        acc0.x = fmaf(ha1.x, x1, acc0.x); acc0.y = fmaf(ha1.y, x1, acc0.y);
        acc0.z = fmaf(ha1.z, x1, acc0.z); acc0.w = fmaf(ha1.w, x1, acc0.w);
        acc1.x = fmaf(hb1.x, x1, acc1.x); acc1.y = fmaf(hb1.y, x1, acc1.y);
        acc1.z = fmaf(hb1.z, x1, acc1.z); acc1.w = fmaf(hb1.w, x1, acc1.w);
        ss += x0 + x1;
    }
    if (j < r1) {
        const int s0 = csr[j];
        const float x0 = __expf(lrelu(aS[s0 * 4 + head] + adh));
        const float4 ha0 = hW4[(size_t)s0 * 32 + cg * 2 + 0];
        const float4 hb0 = hW4[(size_t)s0 * 32 + cg * 2 + 1];
        acc0.x = fmaf(ha0.x, x0, acc0.x); acc0.y = fmaf(ha0.y, x0, acc0.y);
        acc0.z = fmaf(ha0.z, x0, acc0.z); acc0.w = fmaf(ha0.w, x0, acc0.w);
        acc1.x = fmaf(hb0.x, x0, acc1.x); acc1.y = fmaf(hb0.y, x0, acc1.y);
        acc1.z = fmaf(hb0.z, x0, acc1.z); acc1.w = fmaf(hb0.w, x0, acc1.w);
        ss += x0;
    }

    // reduce across the 4 edge-slots (lanes differ in bits 4..5)
#pragma unroll
    for (int off = 16; off <= 32; off <<= 1) {
        acc0.x += __shfl_xor(acc0.x, off); acc0.y += __shfl_xor(acc0.y, off);
        acc0.z += __shfl_xor(acc0.z, off); acc0.w += __shfl_xor(acc0.w, off);
        acc1.x += __shfl_xor(acc1.x, off); acc1.y += __shfl_xor(acc1.y, off);
        acc1.z += __shfl_xor(acc1.z, off); acc1.w += __shfl_xor(acc1.w, off);
        ss += __shfl_xor(ss, off);
    }

    if (slot == 0) {
        const float inv = 1.0f / (ss + 1e-16f);
        const float4 bg0 = bgat4[cg * 2 + 0];
        const float4 bg1 = bgat4[cg * 2 + 1];
        float4 o0, o1;
        o0.x = acc0.x * inv + bg0.x; o0.y = acc0.y * inv + bg0.y;
        o0.z = acc0.z * inv + bg0.z; o0.w = acc0.w * inv + bg0.w;
        o1.x = acc1.x * inv + bg1.x; o1.y = acc1.y * inv + bg1.y;
        o1.z = acc1.z * inv + bg1.z; o1.w = acc1.w * inv + bg1.w;
        gout4[(size_t)n * 32 + cg * 2 + 0] = o0;
        gout4[(size_t)n * 32 + cg * 2 + 1] = o1;
    }
}

// ---------------------------------------------------------------------------
// K_mlp: h2 = relu(gout@W1+b1); logits = h2@W2+b2. One wave per node,
// 16 nodes/block (4 waves x 4 iters), W1 staged in LDS.
// ---------------------------------------------------------------------------
__global__ __launch_bounds__(256) void k_mlp(
    const float* __restrict__ gout,
    const float* __restrict__ W1, const float* __restrict__ b1,
    const float* __restrict__ W2, const float* __restrict__ b2,
    float2* __restrict__ out)
{
    __shared__ __align__(16) float W1l[HID * 64];
    __shared__ __align__(16) float rowbuf[4][HID];
    __shared__ float b1l[64];
    __shared__ float W2l[128];
    __shared__ float b2l[2];

    const int t = threadIdx.x;
    for (int idx = t; idx < HID * 64; idx += 256) W1l[idx] = W1[idx];
    if (t < 64) b1l[t] = b1[t];
    if (t < 128) W2l[t] = W2[t];
    if (t < 2) b2l[t] = b2[t];
    __syncthreads();

    const int w = t >> 6, lane = t & 63;

    for (int it = 0; it < 4; ++it) {
        const int n = blockIdx.x * 16 + w * 4 + it;
        const float2 oa = *(const float2*)&gout[(size_t)n * HID + lane * 2];
        rowbuf[w][lane * 2 + 0] = oa.x;
        rowbuf[w][lane * 2 + 1] = oa.y;

        float acc = b1l[lane];
#pragma unroll 4
        for (int k = 0; k < HID; k += 4) {
            const float4 bv = *(const float4*)&rowbuf[w][k];
            acc = fmaf(bv.x, W1l[(k + 0) * 64 + lane], acc);
            acc = fmaf(bv.y, W1l[(k + 1) * 64 + lane], acc);
            acc = fmaf(bv.z, W1l[(k + 2) * 64 + lane], acc);
            acc = fmaf(bv.w, W1l[(k + 3) * 64 + lane], acc);
        }
        acc = acc > 0.0f ? acc : 0.0f;

        float l0 = acc * W2l[lane * 2 + 0];
        float l1 = acc * W2l[lane * 2 + 1];
#pragma unroll
        for (int off = 32; off >= 1; off >>= 1) {
            l0 += __shfl_xor(l0, off);
            l1 += __shfl_xor(l1, off);
        }
        if (lane == 0) out[n] = make_float2(l0 + b2l[0], l1 + b2l[1]);
    }
}

extern "C" void kernel_launch(void* const* d_in, const int* in_sizes, int n_in,
                              void* d_out, int out_size, void* d_ws, size_t ws_size,
                              hipStream_t stream) {
    const float* x     = (const float*)d_in[0];
    const int*   ei    = (const int*)d_in[1];
    const float* Win   = (const float*)d_in[2];
    const float* bin   = (const float*)d_in[3];
    const float* Wgat  = (const float*)d_in[4];
    const float* attS  = (const float*)d_in[5];
    const float* attD  = (const float*)d_in[6];
    const float* bgat  = (const float*)d_in[7];
    const float* W1    = (const float*)d_in[8];
    const float* b1    = (const float*)d_in[9];
    const float* W2    = (const float*)d_in[10];
    const float* b2    = (const float*)d_in[11];

    char* ws = (char*)d_ws;
    float* hW    = (float*)(ws + HW_OFF);
    float* aS    = (float*)(ws + ASRC_OFF);
    float* aD    = (float*)(ws + ADST_OFF);
    int*   deg   = (int*)(ws + DEG_OFF);
    int*   row   = (int*)(ws + ROW_OFF);
    int*   cur   = (int*)(ws + CUR_OFF);
    int*   bsum  = (int*)(ws + BSUM_OFF);
    int*   csr   = (int*)(ws + CSR_OFF);
    float* gout  = (float*)(ws + GOUT_OFF);

    hipMemsetAsync(ws + DEG_OFF, 0, N * sizeof(int), stream);

    k_proj<<<N / 16, 256, 0, stream>>>(x, Win, bin, Wgat, attS, attD, hW, aS, aD);
    k_hist<<<(TOT + 255) / 256, 256, 0, stream>>>(ei, deg);
    k_scan1<<<SCAN_NB, 256, 0, stream>>>(deg, bsum);
    k_scan2<<<1, 64, 0, stream>>>(bsum, row);
    k_scan3<<<SCAN_NB, 256, 0, stream>>>(deg, bsum, row, cur);
    k_scatter<<<(TOT + 255) / 256, 256, 0, stream>>>(ei, cur, csr);
    k_agg<<<N / 4, 256, 0, stream>>>(row, csr, aS, aD, (const float4*)hW,
                                     (const float4*)bgat, (float4*)gout);
    k_mlp<<<N / 16, 256, 0, stream>>>(gout, W1, b1, W2, b2, (float2*)d_out);
}

// Round 4
// 667.674 us; speedup vs baseline: 3.2617x; 1.1056x over previous
//
#include <hip/hip_runtime.h>

#define DEVFN __device__ __forceinline__

constexpr int N    = 100000;
constexpr int F_IN = 166;
constexpr int HID  = 128;
constexpr int E    = 1600000;
constexpr int TOT  = E + N;          // edges + self-loops

// ---- workspace layout (bytes, all 16B-aligned) ----
constexpr size_t HW_OFF   = 0;            // hW [N,128] f32      51.2 MB
constexpr size_t ASRC_OFF = 51200000;     // a_src [N,4] f32      1.6 MB
constexpr size_t ADST_OFF = 52800000;     // a_dst [N,4] f32      1.6 MB
constexpr size_t DEG_OFF  = 54400000;     // deg [N] i32        400 KB (zeroed)
constexpr size_t ROW_OFF  = 54800000;     // rowstart [N+1] i32
constexpr size_t CUR_OFF  = 55300000;     // cursor [N] i32
constexpr size_t BSUM_OFF = 55700000;     // block sums [128] i32
constexpr size_t CSR_OFF  = 55710000;     // csr_src [TOT] i32   27.2 MB
constexpr size_t GOUT_OFF = 82910016;     // gat out [N,128] f32 51.2 MB

constexpr int SCAN_ELEMS = 1024;
constexpr int SCAN_NB    = (N + SCAN_ELEMS - 1) / SCAN_ELEMS;  // 98

DEVFN float lrelu(float e) { return e > 0.0f ? e : 0.2f * e; }

// ---------------------------------------------------------------------------
// K1: h = relu(x@W_in+b_in), hW = h@W_gat, a_src/a_dst = per-head hW·att
// Tile 32 rows x 128 cols, 256 threads, each thread owns 4 rows x 4 cols.
// x tile and h tile share one LDS buffer (union; h overwrites x after GEMM1).
// Per 2-k step: 4 broadcast ds_read_b64 + 2 global float4 + 32 fma (84% fma).
// ---------------------------------------------------------------------------
__global__ __launch_bounds__(256) void k_proj(
    const float* __restrict__ x, const float* __restrict__ Win,
    const float* __restrict__ bin, const float* __restrict__ Wgat,
    const float* __restrict__ attS, const float* __restrict__ attD,
    float* __restrict__ hW, float* __restrict__ aS, float* __restrict__ aD)
{
    __shared__ __align__(16) float smem[32 * 168];  // xs [32][168]; hs [32][132]
    float* xs = smem;
    float* hs = smem;

    const int t = threadIdx.x;
    const int row0 = blockIdx.x * 32;
    const int cgrp = t & 31, rgrp = t >> 5;
    const int c0 = cgrp * 4;          // 4 cols
    const int r0 = rgrp * 4;          // 4 rows

    // ---- stage x tile (row-major, stride 168), float2 granules ----
    for (int idx = t; idx < 32 * 83; idx += 256) {
        const int r = idx / 83, kk = idx - r * 83;
        const float2 v = *(const float2*)&x[(size_t)(row0 + r) * F_IN + 2 * kk];
        *(float2*)&xs[r * 168 + 2 * kk] = v;
    }
    __syncthreads();

    // ---- GEMM1: h = relu(x@Win + bin) ----
    float acc[4][4];
#pragma unroll
    for (int r = 0; r < 4; ++r)
#pragma unroll
        for (int c = 0; c < 4; ++c) acc[r][c] = 0.0f;

    for (int k = 0; k < F_IN; k += 2) {
        const float4 w0 = *(const float4*)&Win[(k + 0) * HID + c0];
        const float4 w1 = *(const float4*)&Win[(k + 1) * HID + c0];
#pragma unroll
        for (int r = 0; r < 4; ++r) {
            const float2 xv = *(const float2*)&xs[(r0 + r) * 168 + k];
            acc[r][0] = fmaf(xv.x, w0.x, fmaf(xv.y, w1.x, acc[r][0]));
            acc[r][1] = fmaf(xv.x, w0.y, fmaf(xv.y, w1.y, acc[r][1]));
            acc[r][2] = fmaf(xv.x, w0.z, fmaf(xv.y, w1.z, acc[r][2]));
            acc[r][3] = fmaf(xv.x, w0.w, fmaf(xv.y, w1.w, acc[r][3]));
        }
    }

    const float4 bb = *(const float4*)&bin[c0];
    __syncthreads();   // everyone done reading xs; safe to overwrite with hs

#pragma unroll
    for (int r = 0; r < 4; ++r) {
        float4 h;
        h.x = fmaxf(acc[r][0] + bb.x, 0.0f);
        h.y = fmaxf(acc[r][1] + bb.y, 0.0f);
        h.z = fmaxf(acc[r][2] + bb.z, 0.0f);
        h.w = fmaxf(acc[r][3] + bb.w, 0.0f);
        *(float4*)&hs[(r0 + r) * 132 + c0] = h;
    }
    __syncthreads();

    // ---- GEMM2: hW = h@Wgat ----
#pragma unroll
    for (int r = 0; r < 4; ++r)
#pragma unroll
        for (int c = 0; c < 4; ++c) acc[r][c] = 0.0f;

    for (int k = 0; k < HID; k += 2) {
        const float4 w0 = *(const float4*)&Wgat[(k + 0) * HID + c0];
        const float4 w1 = *(const float4*)&Wgat[(k + 1) * HID + c0];
#pragma unroll
        for (int r = 0; r < 4; ++r) {
            const float2 hv = *(const float2*)&hs[(r0 + r) * 132 + k];
            acc[r][0] = fmaf(hv.x, w0.x, fmaf(hv.y, w1.x, acc[r][0]));
            acc[r][1] = fmaf(hv.x, w0.y, fmaf(hv.y, w1.y, acc[r][1]));
            acc[r][2] = fmaf(hv.x, w0.z, fmaf(hv.y, w1.z, acc[r][2]));
            acc[r][3] = fmaf(hv.x, w0.w, fmaf(hv.y, w1.w, acc[r][3]));
        }
    }

    // ---- epilogue: store hW rows; per-head att dots ----
    const float4 atS = *(const float4*)&attS[c0];
    const float4 atD = *(const float4*)&attD[c0];
    const int head = cgrp >> 3;

    float ps[4], pd[4];
#pragma unroll
    for (int r = 0; r < 4; ++r) {
        float4 v;
        v.x = acc[r][0]; v.y = acc[r][1]; v.z = acc[r][2]; v.w = acc[r][3];
        *(float4*)&hW[(size_t)(row0 + r0 + r) * HID + c0] = v;
        ps[r] = v.x * atS.x + v.y * atS.y + v.z * atS.z + v.w * atS.w;
        pd[r] = v.x * atD.x + v.y * atD.y + v.z * atD.z + v.w * atD.w;
    }
#pragma unroll
    for (int off = 1; off <= 4; off <<= 1) {
#pragma unroll
        for (int r = 0; r < 4; ++r) {
            ps[r] += __shfl_xor(ps[r], off);
            pd[r] += __shfl_xor(pd[r], off);
        }
    }
    if ((cgrp & 7) == 0) {
#pragma unroll
        for (int r = 0; r < 4; ++r) {
            const int row = row0 + r0 + r;
            aS[row * 4 + head] = ps[r];
            aD[row * 4 + head] = pd[r];
        }
    }
}

// ---------------------------------------------------------------------------
// CSR build
// ---------------------------------------------------------------------------
__global__ __launch_bounds__(256) void k_hist(const int* __restrict__ ei,
                                              int* __restrict__ deg)
{
    int i = blockIdx.x * 256 + threadIdx.x;
    if (i >= TOT) return;
    int d = (i < E) ? ei[E + i] : (i - E);
    atomicAdd(&deg[d], 1);
}

__global__ __launch_bounds__(256) void k_scan1(const int* __restrict__ deg,
                                               int* __restrict__ bsum)
{
    __shared__ int sd[256];
    const int t = threadIdx.x, b = blockIdx.x;
    int s = 0;
    int i0 = b * SCAN_ELEMS + t * 4;
#pragma unroll
    for (int k = 0; k < 4; ++k) {
        int i = i0 + k;
        s += (i < N) ? deg[i] : 0;
    }
    sd[t] = s;
    __syncthreads();
    for (int off = 128; off >= 1; off >>= 1) {
        if (t < off) sd[t] += sd[t + off];
        __syncthreads();
    }
    if (t == 0) bsum[b] = sd[0];
}

__global__ void k_scan2(int* __restrict__ bsum, int* __restrict__ rowstart)
{
    if (threadIdx.x == 0) {
        int run = 0;
        for (int b = 0; b < SCAN_NB; ++b) {
            int v = bsum[b];
            bsum[b] = run;
            run += v;
        }
        rowstart[N] = run;  // == TOT
    }
}

__global__ __launch_bounds__(256) void k_scan3(const int* __restrict__ deg,
                                               const int* __restrict__ boff,
                                               int* __restrict__ rowstart,
                                               int* __restrict__ cursor)
{
    __shared__ int sd[256];
    const int t = threadIdx.x, b = blockIdx.x;
    const int i0 = b * SCAN_ELEMS + t * 4;
    int d0 = (i0 + 0 < N) ? deg[i0 + 0] : 0;
    int d1 = (i0 + 1 < N) ? deg[i0 + 1] : 0;
    int d2 = (i0 + 2 < N) ? deg[i0 + 2] : 0;
    int d3 = (i0 + 3 < N) ? deg[i0 + 3] : 0;
    int tsum = d0 + d1 + d2 + d3;
    sd[t] = tsum;
    __syncthreads();
    for (int off = 1; off < 256; off <<= 1) {
        int v = (t >= off) ? sd[t - off] : 0;
        __syncthreads();
        sd[t] += v;
        __syncthreads();
    }
    int base = boff[b] + sd[t] - tsum;
    int e0 = base, e1 = base + d0, e2 = e1 + d1, e3 = e2 + d2;
    if (i0 + 0 < N) { rowstart[i0 + 0] = e0; cursor[i0 + 0] = e0; }
    if (i0 + 1 < N) { rowstart[i0 + 1] = e1; cursor[i0 + 1] = e1; }
    if (i0 + 2 < N) { rowstart[i0 + 2] = e2; cursor[i0 + 2] = e2; }
    if (i0 + 3 < N) { rowstart[i0 + 3] = e3; cursor[i0 + 3] = e3; }
}

__global__ __launch_bounds__(256) void k_scatter(const int* __restrict__ ei,
                                                 int* __restrict__ cursor,
                                                 int* __restrict__ csr)
{
    int i = blockIdx.x * 256 + threadIdx.x;
    if (i >= TOT) return;
    int s, d;
    if (i < E) { s = ei[i]; d = ei[E + i]; } else { s = i - E; d = s; }
    int pos = atomicAdd(&cursor[d], 1);
    csr[pos] = s;
}

// ---------------------------------------------------------------------------
// K_agg: one wave per dst node; lane = slot(4) x colgroup(16); 4 edges in
// flight x unroll 2 = 8 outstanding hW-row gathers. No max pass (|e| < 1,
// exp cannot overflow; softmax is shift-invariant). No LDS -> full occupancy.
// ---------------------------------------------------------------------------
__global__ __launch_bounds__(256) void k_agg(
    const int* __restrict__ rowstart, const int* __restrict__ csr,
    const float* __restrict__ aS, const float* __restrict__ aD,
    const float4* __restrict__ hW4, const float4* __restrict__ bgat4,
    float4* __restrict__ gout4)
{
    const int t = threadIdx.x;
    const int n = blockIdx.x * 4 + (t >> 6);
    const int lane = t & 63;
    const int slot = lane >> 4;      // which of 4 parallel edges
    const int cg   = lane & 15;      // colgroup: cols [cg*8, cg*8+8)
    const int head = cg >> 2;

    const int r0 = rowstart[n], r1 = rowstart[n + 1];
    const float adh = aD[n * 4 + head];

    float4 acc0 = {0.f, 0.f, 0.f, 0.f};
    float4 acc1 = {0.f, 0.f, 0.f, 0.f};
    float ss = 0.0f;

    int j = r0 + slot;
    for (; j + 4 < r1; j += 8) {
        const int s0 = csr[j], s1 = csr[j + 4];
        const float x0 = __expf(lrelu(aS[s0 * 4 + head] + adh));
        const float x1 = __expf(lrelu(aS[s1 * 4 + head] + adh));
        const float4 ha0 = hW4[(size_t)s0 * 32 + cg * 2 + 0];
        const float4 hb0 = hW4[(size_t)s0 * 32 + cg * 2 + 1];
        const float4 ha1 = hW4[(size_t)s1 * 32 + cg * 2 + 0];
        const float4 hb1 = hW4[(size_t)s1 * 32 + cg * 2 + 1];
        acc0.x = fmaf(ha0.x, x0, acc0.x); acc0.y = fmaf(ha0.y, x0, acc0.y);
        acc0.z = fmaf(ha0.z, x0, acc0.z); acc0.w = fmaf(ha0.w, x0, acc0.w);
        acc1.x = fmaf(hb0.x, x0, acc1.x); acc1.y = fmaf(hb0.y, x0, acc1.y);
        acc1.z = fmaf(hb0.z, x0, acc1.z); acc1.w = fmaf(hb0.w, x0, acc1.w);
        acc0.x = fmaf(ha1.x, x1, acc0.x); acc0.y = fmaf(ha1.y, x1, acc0.y);
        acc0.z = fmaf(ha1.z, x1, acc0.z); acc0.w = fmaf(ha1.w, x1, acc0.w);
        acc1.x = fmaf(hb1.x, x1, acc1.x); acc1.y = fmaf(hb1.y, x1, acc1.y);
        acc1.z = fmaf(hb1.z, x1, acc1.z); acc1.w = fmaf(hb1.w, x1, acc1.w);
        ss += x0 + x1;
    }
    if (j < r1) {
        const int s0 = csr[j];
        const float x0 = __expf(lrelu(aS[s0 * 4 + head] + adh));
        const float4 ha0 = hW4[(size_t)s0 * 32 + cg * 2 + 0];
        const float4 hb0 = hW4[(size_t)s0 * 32 + cg * 2 + 1];
        acc0.x = fmaf(ha0.x, x0, acc0.x); acc0.y = fmaf(ha0.y, x0, acc0.y);
        acc0.z = fmaf(ha0.z, x0, acc0.z); acc0.w = fmaf(ha0.w, x0, acc0.w);
        acc1.x = fmaf(hb0.x, x0, acc1.x); acc1.y = fmaf(hb0.y, x0, acc1.y);
        acc1.z = fmaf(hb0.z, x0, acc1.z); acc1.w = fmaf(hb0.w, x0, acc1.w);
        ss += x0;
    }

#pragma unroll
    for (int off = 16; off <= 32; off <<= 1) {
        acc0.x += __shfl_xor(acc0.x, off); acc0.y += __shfl_xor(acc0.y, off);
        acc0.z += __shfl_xor(acc0.z, off); acc0.w += __shfl_xor(acc0.w, off);
        acc1.x += __shfl_xor(acc1.x, off); acc1.y += __shfl_xor(acc1.y, off);
        acc1.z += __shfl_xor(acc1.z, off); acc1.w += __shfl_xor(acc1.w, off);
        ss += __shfl_xor(ss, off);
    }

    if (slot == 0) {
        const float inv = 1.0f / (ss + 1e-16f);
        const float4 bg0 = bgat4[cg * 2 + 0];
        const float4 bg1 = bgat4[cg * 2 + 1];
        float4 o0, o1;
        o0.x = acc0.x * inv + bg0.x; o0.y = acc0.y * inv + bg0.y;
        o0.z = acc0.z * inv + bg0.z; o0.w = acc0.w * inv + bg0.w;
        o1.x = acc1.x * inv + bg1.x; o1.y = acc1.y * inv + bg1.y;
        o1.z = acc1.z * inv + bg1.z; o1.w = acc1.w * inv + bg1.w;
        gout4[(size_t)n * 32 + cg * 2 + 0] = o0;
        gout4[(size_t)n * 32 + cg * 2 + 1] = o1;
    }
}

// ---------------------------------------------------------------------------
// K_mlp: h2 = relu(gout@W1+b1); logits = h2@W2+b2. One wave per node,
// 16 nodes/block (4 waves x 4 iters), W1 staged in LDS.
// ---------------------------------------------------------------------------
__global__ __launch_bounds__(256) void k_mlp(
    const float* __restrict__ gout,
    const float* __restrict__ W1, const float* __restrict__ b1,
    const float* __restrict__ W2, const float* __restrict__ b2,
    float2* __restrict__ out)
{
    __shared__ __align__(16) float W1l[HID * 64];
    __shared__ __align__(16) float rowbuf[4][HID];
    __shared__ float b1l[64];
    __shared__ float W2l[128];
    __shared__ float b2l[2];

    const int t = threadIdx.x;
    for (int idx = t; idx < HID * 64; idx += 256) W1l[idx] = W1[idx];
    if (t < 64) b1l[t] = b1[t];
    if (t < 128) W2l[t] = W2[t];
    if (t < 2) b2l[t] = b2[t];
    __syncthreads();

    const int w = t >> 6, lane = t & 63;

    for (int it = 0; it < 4; ++it) {
        const int n = blockIdx.x * 16 + w * 4 + it;
        const float2 oa = *(const float2*)&gout[(size_t)n * HID + lane * 2];
        rowbuf[w][lane * 2 + 0] = oa.x;
        rowbuf[w][lane * 2 + 1] = oa.y;

        float acc = b1l[lane];
#pragma unroll 4
        for (int k = 0; k < HID; k += 4) {
            const float4 bv = *(const float4*)&rowbuf[w][k];
            acc = fmaf(bv.x, W1l[(k + 0) * 64 + lane], acc);
            acc = fmaf(bv.y, W1l[(k + 1) * 64 + lane], acc);
            acc = fmaf(bv.z, W1l[(k + 2) * 64 + lane], acc);
            acc = fmaf(bv.w, W1l[(k + 3) * 64 + lane], acc);
        }
        acc = acc > 0.0f ? acc : 0.0f;

        float l0 = acc * W2l[lane * 2 + 0];
        float l1 = acc * W2l[lane * 2 + 1];
#pragma unroll
        for (int off = 32; off >= 1; off >>= 1) {
            l0 += __shfl_xor(l0, off);
            l1 += __shfl_xor(l1, off);
        }
        if (lane == 0) out[n] = make_float2(l0 + b2l[0], l1 + b2l[1]);
    }
}

extern "C" void kernel_launch(void* const* d_in, const int* in_sizes, int n_in,
                              void* d_out, int out_size, void* d_ws, size_t ws_size,
                              hipStream_t stream) {
    const float* x     = (const float*)d_in[0];
    const int*   ei    = (const int*)d_in[1];
    const float* Win   = (const float*)d_in[2];
    const float* bin   = (const float*)d_in[3];
    const float* Wgat  = (const float*)d_in[4];
    const float* attS  = (const float*)d_in[5];
    const float* attD  = (const float*)d_in[6];
    const float* bgat  = (const float*)d_in[7];
    const float* W1    = (const float*)d_in[8];
    const float* b1    = (const float*)d_in[9];
    const float* W2    = (const float*)d_in[10];
    const float* b2    = (const float*)d_in[11];

    char* ws = (char*)d_ws;
    float* hW    = (float*)(ws + HW_OFF);
    float* aS    = (float*)(ws + ASRC_OFF);
    float* aD    = (float*)(ws + ADST_OFF);
    int*   deg   = (int*)(ws + DEG_OFF);
    int*   row   = (int*)(ws + ROW_OFF);
    int*   cur   = (int*)(ws + CUR_OFF);
    int*   bsum  = (int*)(ws + BSUM_OFF);
    int*   csr   = (int*)(ws + CSR_OFF);
    float* gout  = (float*)(ws + GOUT_OFF);

    hipMemsetAsync(ws + DEG_OFF, 0, N * sizeof(int), stream);

    k_proj<<<N / 32, 256, 0, stream>>>(x, Win, bin, Wgat, attS, attD, hW, aS, aD);
    k_hist<<<(TOT + 255) / 256, 256, 0, stream>>>(ei, deg);
    k_scan1<<<SCAN_NB, 256, 0, stream>>>(deg, bsum);
    k_scan2<<<1, 64, 0, stream>>>(bsum, row);
    k_scan3<<<SCAN_NB, 256, 0, stream>>>(deg, bsum, row, cur);
    k_scatter<<<(TOT + 255) / 256, 256, 0, stream>>>(ei, cur, csr);
    k_agg<<<N / 4, 256, 0, stream>>>(row, csr, aS, aD, (const float4*)hW,
                                     (const float4*)bgat, (float4*)gout);
    k_mlp<<<N / 16, 256, 0, stream>>>(gout, W1, b1, W2, b2, (float2*)d_out);
}